// Round 6
// baseline (140.814 us; speedup 1.0000x reference)
//
#include <hip/hip_runtime.h>
#include <math.h>

#define N_LAYERS 200
#define KSIZE 7
#define L_IN 1388
#define FC_IN 188
#define FC_OUT 91
#define NT 256        // 4 waves per row
#define NW 4
#define RMAX 6
#define NSTAGES 25    // 8 layers per stage, margin 48

// Valid row length after stage s (stage s = layers [8s, 8s+8)).
constexpr int len_end(int s) { return 1340 - 48 * s; }
// Values per lane for stage s: region = own + 48 margin; last wave owns the
// remainder (largest). 64*R >= own_max + 48.
constexpr int stage_R(int s) {
    const int l = len_end(s);
    const int q = l / 4;
    const int own3 = l - 3 * q;
    return (own3 + 48 + 63) / 64;
}

// One stage of layers [i0,i1) with R values/lane, shfl-pipelined halo.
//  - r[0..R-1]: positions base + lane*R + k of the current layer's input.
//  - h[0..5]:   positions base + lane*R + R + t, fetched the PREVIOUS layer
//               (or primed at load/repack).
//  - Ascending in-place update is safe (output k overwrites input k only).
//  - Garbage beyond the region creeps left 6/layer; the 48-margin absorbs
//    exactly 8 layers. Out-of-wave shfl lanes return garbage -> creep zone.
template<int R, bool RELU>
__device__ __forceinline__ void run_stage(float (&r)[RMAX], float (&h)[6],
                                          const float* __restrict__ cw,
                                          const float* __restrict__ cb,
                                          int i0, int i1)
{
    constexpr int S = (R < 6) ? R : 6;
    float w[KSIZE], b;
#pragma unroll
    for (int d = 0; d < KSIZE; ++d) w[d] = cw[i0 * KSIZE + d];
    b = cb[i0];

#pragma unroll 1
    for (int i = i0; i < i1; ++i) {
        // update k = 0..S-1
#pragma unroll
        for (int k = 0; k < S; ++k) {
            float acc = b;
#pragma unroll
            for (int d = 0; d < KSIZE; ++d) {
                const int m = k + d;
                const float v = (m < R) ? r[m] : h[m - R];  // compile-time select
                acc = fmaf(w[d], v, acc);
            }
            r[k] = RELU ? fmaxf(acc, 0.0f) : acc;
        }

        // next layer's halo: just-updated r[..] of lanes +1..+3
        float hn[6];
#pragma unroll
        for (int t = 0; t < 6; ++t)
            hn[t] = __shfl_down(r[t % R], 1 + t / R);

        // prefetch next layer's weights (uniform -> scalar loads)
        float w2[KSIZE], b2;
        const int ip = (i + 1 < i1) ? (i + 1) : i;
#pragma unroll
        for (int d = 0; d < KSIZE; ++d) w2[d] = cw[ip * KSIZE + d];
        b2 = cb[ip];

        // update k = S..R-1 (consumes h fetched one layer ago; empty if R<=6)
#pragma unroll
        for (int k = S; k < R; ++k) {
            float acc = b;
#pragma unroll
            for (int d = 0; d < KSIZE; ++d) {
                const int m = k + d;
                const float v = (m < R) ? r[m] : h[m - R];
                acc = fmaf(w[d], v, acc);
            }
            r[k] = RELU ? fmaxf(acc, 0.0f) : acc;
        }

#pragma unroll
        for (int t = 0; t < 6; ++t) h[t] = hn[t];
#pragma unroll
        for (int d = 0; d < KSIZE; ++d) w[d] = w2[d];
        b = b2;
    }
}

// Cross-wave repack at a stage boundary: write owned valid values at global
// row positions, barrier, read next stage's region + halo, barrier.
template<int Ro, int Rn>
__device__ __forceinline__ void repack(float (&r)[RMAX], float (&h)[6],
                                       float* lbuf, int lane, int wid,
                                       int len1, int q1, int q2)
{
    const int base_o = wid * q1;
    const int bound  = (wid == 3) ? len1 : base_o + q1;
#pragma unroll
    for (int k = 0; k < Ro; ++k) {
        const int g = base_o + lane * Ro + k;
        if (g < bound) lbuf[g] = r[k];
    }
    __syncthreads();
    const int base_n = wid * q2;
#pragma unroll
    for (int k = 0; k < Rn; ++k) r[k] = lbuf[base_n + lane * Rn + k];
#pragma unroll
    for (int t = 0; t < 6; ++t) h[t] = lbuf[base_n + lane * Rn + Rn + t];
    __syncthreads();
}

template<int S>
struct Chain {
    __device__ static __forceinline__ void run(float (&r)[RMAX], float (&h)[6],
        const float* __restrict__ cw, const float* __restrict__ cb,
        float* lbuf, int lane, int wid)
    {
        constexpr int R = stage_R(S);
        run_stage<R, true>(r, h, cw, cb, 8 * S, 8 * S + 8);
        constexpr int len1 = len_end(S);
        constexpr int q1 = len1 / 4;
        constexpr int q2 = len_end(S + 1) / 4;
        repack<R, stage_R(S + 1)>(r, h, lbuf, lane, wid, len1, q1, q2);
        Chain<S + 1>::run(r, h, cw, cb, lbuf, lane, wid);
    }
};

template<>
struct Chain<NSTAGES - 1> {
    __device__ static __forceinline__ void run(float (&r)[RMAX], float (&h)[6],
        const float* __restrict__ cw, const float* __restrict__ cb,
        float* lbuf, int lane, int wid)
    {
        constexpr int R = stage_R(NSTAGES - 1);  // 2
        run_stage<R, true >(r, h, cw, cb, 8 * (NSTAGES - 1), N_LAYERS - 1);
        run_stage<R, false>(r, h, cw, cb, N_LAYERS - 1, N_LAYERS);
        // final gather: owned values -> lbuf[0..188)
        constexpr int len1 = len_end(NSTAGES - 1);  // 188
        constexpr int q1 = len1 / 4;                // 47
        const int base_o = wid * q1;
        const int bound  = (wid == 3) ? len1 : base_o + q1;
#pragma unroll
        for (int k = 0; k < R; ++k) {
            const int g = base_o + lane * R + k;
            if (g < bound) lbuf[g] = r[k];
        }
        __syncthreads();
    }
};

__global__ __launch_bounds__(NT) void conv_chain_kernel(
    const float* __restrict__ x,
    const float* __restrict__ conv_w,
    const float* __restrict__ conv_b,
    const float* __restrict__ fc_w,
    const float* __restrict__ fc_b,
    float* __restrict__ out)
{
    // max repack read: 3*(1292/4) + 64*6 + 5 = 1358 -> 1408 floats (5.5 KB)
    __shared__ __align__(16) float lbuf[1408];

    const int row  = blockIdx.x;
    const int tid  = threadIdx.x;
    const int lane = tid & 63;
    const int wid  = tid >> 6;

    // Stage-0 region load from global; wave w base = w * (1340/4) = 335w.
    float r[RMAX], h[6];
    const float* xr = x + (size_t)row * L_IN;
    constexpr int R0 = stage_R(0);          // 6
    const int c0 = wid * (len_end(0) / 4);  // 0,335,670,1005
#pragma unroll
    for (int k = 0; k < R0; ++k) {
        const int p = c0 + lane * R0 + k;
        r[k] = (p < L_IN) ? xr[p] : 0.0f;
    }
#pragma unroll
    for (int t = 0; t < 6; ++t) {
        const int p = c0 + lane * R0 + R0 + t;
        h[t] = (p < L_IN) ? xr[p] : 0.0f;
    }

    Chain<0>::run(r, h, conv_w, conv_b, lbuf, lane, wid);

    // FC(188 -> 91) + sigmoid.
    if (tid < FC_OUT) {
        float acc = fc_b[tid];
        const float4* wp = (const float4*)(fc_w + tid * FC_IN);  // 752B rows: 16B-aligned
        const float4* hp = (const float4*)lbuf;
#pragma unroll 4
        for (int q = 0; q < FC_IN / 4; ++q) {
            const float4 hv = hp[q];
            const float4 wv = wp[q];
            acc = fmaf(wv.x, hv.x, acc);
            acc = fmaf(wv.y, hv.y, acc);
            acc = fmaf(wv.z, hv.z, acc);
            acc = fmaf(wv.w, hv.w, acc);
        }
        out[(size_t)row * FC_OUT + tid] = 1.0f / (1.0f + expf(-acc));
    }
}

extern "C" void kernel_launch(void* const* d_in, const int* in_sizes, int n_in,
                              void* d_out, int out_size, void* d_ws, size_t ws_size,
                              hipStream_t stream) {
    const float* x      = (const float*)d_in[0];
    const float* conv_w = (const float*)d_in[1];
    const float* conv_b = (const float*)d_in[2];
    const float* fc_w   = (const float*)d_in[3];
    const float* fc_b   = (const float*)d_in[4];
    float* outp = (float*)d_out;

    const int batch = in_sizes[0] / L_IN;  // 1024 rows, 4 waves each
    conv_chain_kernel<<<batch, NT, 0, stream>>>(x, conv_w, conv_b, fc_w, fc_b, outp);
}